// Round 7
// baseline (191.918 us; speedup 1.0000x reference)
//
#include <hip/hip_runtime.h>
#include <math.h>

#define NBLK 1024  // k_main: 1024 blocks x 256 thr; block = 128 images x 2 col-halves

// ws layout (floats): [0..2047] partial[1024 blocks][2] (sum, sumsq)

__device__ __forceinline__ float med3f(float a, float b, float c) {
  return __builtin_amdgcn_fmed3f(a, b, c);
}
__device__ __forceinline__ float min3f(float a, float b, float c) { return fminf(fminf(a, b), c); }
__device__ __forceinline__ float max3f(float a, float b, float c) { return fmaxf(fmaxf(a, b), c); }

__device__ __forceinline__ unsigned bf16rne(float f) {  // RNE f32->bf16 (finite inputs)
  const unsigned b = __float_as_uint(f);
  return (b + 0x7fffu + ((b >> 16) & 1u)) >> 16;
}
__device__ __forceinline__ float bflo(unsigned u) { return __uint_as_float(u << 16); }
__device__ __forceinline__ float bfhi(unsigned u) { return __uint_as_float(u & 0xffff0000u); }

// ---------------------------------------------------------------------------
// Fold shift + FC into W'[c] for pixel p (math validated on HW R1..R6).
__device__ __forceinline__ void fold_weights(int p, const float* __restrict__ fc_w,
                                             float sx, float sy, float* __restrict__ w8) {
  const int y = p >> 4, x = p & 15;
  const int dY = (sy > 1.0f) ? 2 : 1;
  const int dX = (sx > 1.0f) ? 2 : 1;
  const float wy1 = (float)dY - sy, wy0 = 1.0f - wy1;
  const float wx1 = (float)dX - sx, wx0 = 1.0f - wx1;
  const int   iys[2] = { y + dY - 1, y + dY };
  const float wys[2] = { wy1, wy0 };
  const int   jxs[2] = { x + dX - 1, x + dX };
  const float wxs[2] = { wx1, wx0 };
  #pragma unroll
  for (int c = 0; c < 8; ++c) {
    float acc = 0.0f;
    #pragma unroll
    for (int a = 0; a < 2; ++a) {
      if (iys[a] < 0 || iys[a] >= 8) continue;
      #pragma unroll
      for (int b = 0; b < 2; ++b) {
        if (jxs[b] < 0 || jxs[b] >= 16) continue;
        acc += wys[a] * wxs[b] * fc_w[c * 128 + iys[a] * 16 + jxs[b]];
      }
    }
    w8[c] = acc;
  }
}

// ---------------------------------------------------------------------------
// K1: 2 threads per image (column halves). Waves 0-1: cols 0-7 of images
// b*128..b*128+127; waves 2-3: cols 8-15 of the SAME images. Rotating 4-row
// x 10-col register window (no spill), medians in registers, dot weights as
// bf16x8 per pixel read with ONE wave-uniform ds_read_b128. Halves combined
// through a conflict-free class-major LDS buffer; half-0 threads store final
// raw dots. Per-block (sum,sumsq) partials to ws.
__global__ __launch_bounds__(256, 4) void k_main(const float* __restrict__ x,
                                                 const float* __restrict__ fcw,
                                                 const float* __restrict__ xs,
                                                 const float* __restrict__ ys,
                                                 float* __restrict__ out,
                                                 float* __restrict__ partial) {
  __shared__ unsigned wlds[2][64][4];  // [half][r*8+j][4 u32] bf16-packed weights (2KB)
  __shared__ float accbuf[8][128];     // class-major half-1 partial dots (4KB)
  __shared__ float sred[8];
  const int tid  = threadIdx.x;
  const int w    = tid >> 6, l = tid & 63;
  const int half = w >> 1;             // wave-uniform column half
  const int il   = tid & 127;         // image-local index 0..127
  const int img  = blockIdx.x * 128 + il;
  const int c0   = half * 8;
  const float* __restrict__ xi = x + (size_t)img * 128;

  // rotating window: rows[slot][idx], idx k <-> column c0-1+k (10 cols)
  float rows[4][10];
#define LOADROW(rr, s)                                                        \
  {                                                                           \
    const float4 va = *(const float4*)&xi[(rr) * 16 + c0];                    \
    const float4 vb = *(const float4*)&xi[(rr) * 16 + c0 + 4];                \
    rows[s][1] = va.x; rows[s][2] = va.y; rows[s][3] = va.z; rows[s][4] = va.w;\
    rows[s][5] = vb.x; rows[s][6] = vb.y; rows[s][7] = vb.z; rows[s][8] = vb.w;\
    if (half) { rows[s][0] = xi[(rr) * 16 + 7]; rows[s][9] = 0.0f; }          \
    else      { rows[s][0] = 0.0f; rows[s][9] = xi[(rr) * 16 + 8]; }          \
  }

  LOADROW(0, 0)
  LOADROW(1, 1)

  // fold W' into bf16-packed LDS: thread tid<128 handles pixel p=tid
  const float sx = xs[0] + 0.5f, sy = ys[0] + 0.5f;
  if (tid < 128) {
    float w8[8];
    fold_weights(tid, fcw, sx, sy, w8);
    const int ph = (tid & 15) >> 3;
    const int lp = (tid >> 4) * 8 + (tid & 7);
    uint4 u;
    u.x = bf16rne(w8[0]) | (bf16rne(w8[1]) << 16);
    u.y = bf16rne(w8[2]) | (bf16rne(w8[3]) << 16);
    u.z = bf16rne(w8[4]) | (bf16rne(w8[5]) << 16);
    u.w = bf16rne(w8[6]) | (bf16rne(w8[7]) << 16);
    *(uint4*)&wlds[ph][lp][0] = u;
  }
  __syncthreads();

  float acc[8];
  #pragma unroll
  for (int c = 0; c < 8; ++c) acc[c] = 0.0f;
  float ssum = 0.0f, ssq = 0.0f;

  #pragma unroll
  for (int r = 0; r < 8; ++r) {
    if (r < 6) LOADROW(r + 2, (r + 2) & 3)
    // vertical sort3 over 10 columns (zero rows outside [0,7])
    float lo[10], mi[10], hi[10];
    #pragma unroll
    for (int k = 0; k < 10; ++k) {
      const float a = (r == 0) ? 0.0f : rows[(r - 1) & 3][k];
      const float b = rows[r & 3][k];
      const float d = (r == 7) ? 0.0f : rows[(r + 1) & 3][k];
      lo[k] = min3f(a, b, d);
      mi[k] = med3f(a, b, d);
      hi[k] = max3f(a, b, d);
    }
    // 8 output pixels: idx j+1 <-> col c0+j
    #pragma unroll
    for (int j = 0; j < 8; ++j) {
      const float mx  = max3f(lo[j], lo[j + 1], lo[j + 2]);
      const float md  = med3f(mi[j], mi[j + 1], mi[j + 2]);
      const float mn  = min3f(hi[j], hi[j + 1], hi[j + 2]);
      const float med = med3f(mx, md, mn);  // exact lower-median of 9
      ssum += med;
      ssq = fmaf(med, med, ssq);
      const uint4 u = *(const uint4*)&wlds[half][r * 8 + j][0];  // broadcast b128
      acc[0] = fmaf(med, bflo(u.x), acc[0]);
      acc[1] = fmaf(med, bfhi(u.x), acc[1]);
      acc[2] = fmaf(med, bflo(u.y), acc[2]);
      acc[3] = fmaf(med, bfhi(u.y), acc[3]);
      acc[4] = fmaf(med, bflo(u.z), acc[4]);
      acc[5] = fmaf(med, bfhi(u.z), acc[5]);
      acc[6] = fmaf(med, bflo(u.w), acc[6]);
      acc[7] = fmaf(med, bfhi(u.w), acc[7]);
    }
  }
#undef LOADROW

  // wave stats reduce
  #pragma unroll
  for (int off = 32; off; off >>= 1) {
    ssum += __shfl_xor(ssum, off, 64);
    ssq  += __shfl_xor(ssq,  off, 64);
  }
  if (l == 0) { sred[w] = ssum; sred[4 + w] = ssq; }

  // half-1 partial dots -> class-major LDS (conflict-free b32 writes)
  if (half) {
    #pragma unroll
    for (int c = 0; c < 8; ++c) accbuf[c][il] = acc[c];
  }
  __syncthreads();

  if (!half) {
    #pragma unroll
    for (int c = 0; c < 8; ++c) acc[c] += accbuf[c][il];
    float4* o4 = (float4*)&out[(size_t)img * 8];
    o4[0] = make_float4(acc[0], acc[1], acc[2], acc[3]);
    o4[1] = make_float4(acc[4], acc[5], acc[6], acc[7]);
  }
  if (tid == 0) partial[2 * blockIdx.x]     = (sred[0] + sred[1]) + (sred[2] + sred[3]);
  if (tid == 1) partial[2 * blockIdx.x + 1] = (sred[4] + sred[5]) + (sred[6] + sred[7]);
}

// ---------------------------------------------------------------------------
// K2: each of 256 blocks redundantly reduces partial[2048] (L2-hot),
// recomputes the f32 W' fold for per-class sums, then scales 4 float4/thread:
// out = alpha*dot + (beta*wsum[c] + fcb[c]).
__global__ __launch_bounds__(256) void k_scale(float* __restrict__ out,
                                               const float* __restrict__ partial,
                                               const float* __restrict__ fcw,
                                               const float* __restrict__ xs,
                                               const float* __restrict__ ys,
                                               const float* __restrict__ fcb,
                                               const float* __restrict__ bnw,
                                               const float* __restrict__ bnb) {
  __shared__ float sred[8];
  __shared__ float wred[4][8];
  __shared__ float fin[2];
  const int tid = threadIdx.x;
  const int w = tid >> 6, l = tid & 63;

  // batch stats: 1024 block-pairs / 256 threads = 4 each
  float s = 0.0f, q = 0.0f;
  #pragma unroll
  for (int k = 0; k < 4; ++k) {
    const int idx = tid + 256 * k;
    s += partial[2 * idx];
    q += partial[2 * idx + 1];
  }
  #pragma unroll
  for (int off = 32; off; off >>= 1) {
    s += __shfl_xor(s, off, 64);
    q += __shfl_xor(q, off, 64);
  }

  // redundant W' fold for per-class sums (threads 0..127 contribute)
  float v[8];
  if (tid < 128) {
    fold_weights(tid, fcw, xs[0] + 0.5f, ys[0] + 0.5f, v);
  } else {
    #pragma unroll
    for (int c = 0; c < 8; ++c) v[c] = 0.0f;
  }
  #pragma unroll
  for (int c = 0; c < 8; ++c) {
    #pragma unroll
    for (int off = 32; off; off >>= 1) v[c] += __shfl_xor(v[c], off, 64);
  }

  if (l == 0) {
    sred[w] = s; sred[4 + w] = q;
    #pragma unroll
    for (int c = 0; c < 8; ++c) wred[w][c] = v[c];
  }
  __syncthreads();
  if (tid == 0) {
    const float S = (sred[0] + sred[1]) + (sred[2] + sred[3]);
    const float Q = (sred[4] + sred[5]) + (sred[6] + sred[7]);
    const float N = 16777216.0f;  // 131072*128
    const float mm = S / N;
    const float vv = Q / N - mm * mm;
    const float a = bnw[0] / sqrtf(vv + 1e-5f);
    fin[0] = a;
    fin[1] = bnb[0] - mm * a;
  }
  __syncthreads();
  const float alpha = fin[0], beta = fin[1];

  float cv[8];
  #pragma unroll
  for (int c = 0; c < 8; ++c) {
    const float wsum = (wred[0][c] + wred[1][c]) + (wred[2][c] + wred[3][c]);
    cv[c] = fmaf(beta, wsum, fcb[c]);
  }
  const float4 cv0 = make_float4(cv[0], cv[1], cv[2], cv[3]);
  const float4 cv1 = make_float4(cv[4], cv[5], cv[6], cv[7]);

  float4* o4 = (float4*)out;
  const int base = (blockIdx.x * 256 + tid) * 4;  // 4 float4 per thread
  #pragma unroll
  for (int k = 0; k < 4; ++k) {
    const int i = base + k;
    const float4 c = (i & 1) ? cv1 : cv0;
    float4 ov = o4[i];
    ov.x = fmaf(alpha, ov.x, c.x);
    ov.y = fmaf(alpha, ov.y, c.y);
    ov.z = fmaf(alpha, ov.z, c.z);
    ov.w = fmaf(alpha, ov.w, c.w);
    o4[i] = ov;
  }
}

// ---------------------------------------------------------------------------
extern "C" void kernel_launch(void* const* d_in, const int* in_sizes, int n_in,
                              void* d_out, int out_size, void* d_ws, size_t ws_size,
                              hipStream_t stream) {
  const float* x   = (const float*)d_in[0];
  const float* bnw = (const float*)d_in[1];
  const float* bnb = (const float*)d_in[2];
  const float* xs  = (const float*)d_in[3];
  const float* ys  = (const float*)d_in[4];
  const float* fcw = (const float*)d_in[5];
  const float* fcb = (const float*)d_in[6];
  float* out = (float*)d_out;
  float* ws  = (float*)d_ws;

  float* partial = ws;  // 2048 floats

  hipLaunchKernelGGL(k_main,  dim3(NBLK), dim3(256), 0, stream, x, fcw, xs, ys, out, partial);
  hipLaunchKernelGGL(k_scale, dim3(256),  dim3(256), 0, stream, out, partial, fcw, xs, ys, fcb, bnw, bnb);
}

// Round 8
// 93.293 us; speedup vs baseline: 2.0571x; 2.0571x over previous
//
#include <hip/hip_runtime.h>
#include <math.h>

#define NBLK 1024  // k_main: 1024 blocks x 256 thr; block = 128 images x 2 col-halves

// ws layout (floats): [0..2047] partial[1024 blocks][2] (sum, sumsq)

__device__ __forceinline__ float med3f(float a, float b, float c) {
  return __builtin_amdgcn_fmed3f(a, b, c);
}
__device__ __forceinline__ float min3f(float a, float b, float c) { return fminf(fminf(a, b), c); }
__device__ __forceinline__ float max3f(float a, float b, float c) { return fmaxf(fmaxf(a, b), c); }

__device__ __forceinline__ unsigned bf16rne(float f) {  // RNE f32->bf16 (finite inputs)
  const unsigned b = __float_as_uint(f);
  return (b + 0x7fffu + ((b >> 16) & 1u)) >> 16;
}
__device__ __forceinline__ float bflo(unsigned u) { return __uint_as_float(u << 16); }
__device__ __forceinline__ float bfhi(unsigned u) { return __uint_as_float(u & 0xffff0000u); }

// ---------------------------------------------------------------------------
// Fold shift + FC into W'[c] for pixel p (math validated on HW R1..R7).
__device__ __forceinline__ void fold_weights(int p, const float* __restrict__ fc_w,
                                             float sx, float sy, float* __restrict__ w8) {
  const int y = p >> 4, x = p & 15;
  const int dY = (sy > 1.0f) ? 2 : 1;
  const int dX = (sx > 1.0f) ? 2 : 1;
  const float wy1 = (float)dY - sy, wy0 = 1.0f - wy1;
  const float wx1 = (float)dX - sx, wx0 = 1.0f - wx1;
  const int   iys[2] = { y + dY - 1, y + dY };
  const float wys[2] = { wy1, wy0 };
  const int   jxs[2] = { x + dX - 1, x + dX };
  const float wxs[2] = { wx1, wx0 };
  #pragma unroll
  for (int c = 0; c < 8; ++c) {
    float acc = 0.0f;
    #pragma unroll
    for (int a = 0; a < 2; ++a) {
      if (iys[a] < 0 || iys[a] >= 8) continue;
      #pragma unroll
      for (int b = 0; b < 2; ++b) {
        if (jxs[b] < 0 || jxs[b] >= 16) continue;
        acc += wys[a] * wxs[b] * fc_w[c * 128 + iys[a] * 16 + jxs[b]];
      }
    }
    w8[c] = acc;
  }
}

// ---------------------------------------------------------------------------
// K1: 2 threads per image (column halves). Waves 0-1: cols 0-7 of images
// b*128..b*128+127; waves 2-3: cols 8-15 of the SAME images. Rotating 4-row
// x 10-col register window (~100 VGPR, fits the 128 cap from
// __launch_bounds__(256,2) with NO spill — R7's (256,4) cap of 64 caused the
// 190us spill disaster). Medians in registers; dot weights bf16x8 per pixel
// via ONE wave-uniform ds_read_b128. Halves combined through class-major LDS.
__global__ __launch_bounds__(256, 2) void k_main(const float* __restrict__ x,
                                                 const float* __restrict__ fcw,
                                                 const float* __restrict__ xs,
                                                 const float* __restrict__ ys,
                                                 float* __restrict__ out,
                                                 float* __restrict__ partial) {
  __shared__ unsigned wlds[2][64][4];  // [half][r*8+j][4 u32] bf16-packed weights (2KB)
  __shared__ float accbuf[8][128];     // class-major half-1 partial dots (4KB)
  __shared__ float sred[8];
  const int tid  = threadIdx.x;
  const int w    = tid >> 6, l = tid & 63;
  const int half = w >> 1;             // wave-uniform column half
  const int il   = tid & 127;          // image-local index 0..127
  const int img  = blockIdx.x * 128 + il;
  const int c0   = half * 8;
  const float* __restrict__ xi = x + (size_t)img * 128;

  // rotating window: rows[slot][idx], idx k <-> column c0-1+k (10 cols)
  float rows[4][10];
#define LOADROW(rr, s)                                                        \
  {                                                                           \
    const float4 va = *(const float4*)&xi[(rr) * 16 + c0];                    \
    const float4 vb = *(const float4*)&xi[(rr) * 16 + c0 + 4];                \
    rows[s][1] = va.x; rows[s][2] = va.y; rows[s][3] = va.z; rows[s][4] = va.w;\
    rows[s][5] = vb.x; rows[s][6] = vb.y; rows[s][7] = vb.z; rows[s][8] = vb.w;\
    if (half) { rows[s][0] = xi[(rr) * 16 + 7]; rows[s][9] = 0.0f; }          \
    else      { rows[s][0] = 0.0f; rows[s][9] = xi[(rr) * 16 + 8]; }          \
  }

  LOADROW(0, 0)
  LOADROW(1, 1)

  // fold W' into bf16-packed LDS: thread tid<128 handles pixel p=tid
  const float sx = xs[0] + 0.5f, sy = ys[0] + 0.5f;
  if (tid < 128) {
    float w8[8];
    fold_weights(tid, fcw, sx, sy, w8);
    const int ph = (tid & 15) >> 3;
    const int lp = (tid >> 4) * 8 + (tid & 7);
    uint4 u;
    u.x = bf16rne(w8[0]) | (bf16rne(w8[1]) << 16);
    u.y = bf16rne(w8[2]) | (bf16rne(w8[3]) << 16);
    u.z = bf16rne(w8[4]) | (bf16rne(w8[5]) << 16);
    u.w = bf16rne(w8[6]) | (bf16rne(w8[7]) << 16);
    *(uint4*)&wlds[ph][lp][0] = u;
  }
  __syncthreads();

  float acc[8];
  #pragma unroll
  for (int c = 0; c < 8; ++c) acc[c] = 0.0f;
  float ssum = 0.0f, ssq = 0.0f;

  #pragma unroll
  for (int r = 0; r < 8; ++r) {
    if (r < 6) LOADROW(r + 2, (r + 2) & 3)
    // vertical sort3 over 10 columns (zero rows outside [0,7])
    float lo[10], mi[10], hi[10];
    #pragma unroll
    for (int k = 0; k < 10; ++k) {
      const float a = (r == 0) ? 0.0f : rows[(r - 1) & 3][k];
      const float b = rows[r & 3][k];
      const float d = (r == 7) ? 0.0f : rows[(r + 1) & 3][k];
      lo[k] = min3f(a, b, d);
      mi[k] = med3f(a, b, d);
      hi[k] = max3f(a, b, d);
    }
    // 8 output pixels: idx j+1 <-> col c0+j
    #pragma unroll
    for (int j = 0; j < 8; ++j) {
      const float mx  = max3f(lo[j], lo[j + 1], lo[j + 2]);
      const float md  = med3f(mi[j], mi[j + 1], mi[j + 2]);
      const float mn  = min3f(hi[j], hi[j + 1], hi[j + 2]);
      const float med = med3f(mx, md, mn);  // exact lower-median of 9
      ssum += med;
      ssq = fmaf(med, med, ssq);
      const uint4 u = *(const uint4*)&wlds[half][r * 8 + j][0];  // broadcast b128
      acc[0] = fmaf(med, bflo(u.x), acc[0]);
      acc[1] = fmaf(med, bfhi(u.x), acc[1]);
      acc[2] = fmaf(med, bflo(u.y), acc[2]);
      acc[3] = fmaf(med, bfhi(u.y), acc[3]);
      acc[4] = fmaf(med, bflo(u.z), acc[4]);
      acc[5] = fmaf(med, bfhi(u.z), acc[5]);
      acc[6] = fmaf(med, bflo(u.w), acc[6]);
      acc[7] = fmaf(med, bfhi(u.w), acc[7]);
    }
  }
#undef LOADROW

  // wave stats reduce
  #pragma unroll
  for (int off = 32; off; off >>= 1) {
    ssum += __shfl_xor(ssum, off, 64);
    ssq  += __shfl_xor(ssq,  off, 64);
  }
  if (l == 0) { sred[w] = ssum; sred[4 + w] = ssq; }

  // half-1 partial dots -> class-major LDS (2 lanes/bank = conflict-free)
  if (half) {
    #pragma unroll
    for (int c = 0; c < 8; ++c) accbuf[c][il] = acc[c];
  }
  __syncthreads();

  if (!half) {
    #pragma unroll
    for (int c = 0; c < 8; ++c) acc[c] += accbuf[c][il];
    float4* o4 = (float4*)&out[(size_t)img * 8];
    o4[0] = make_float4(acc[0], acc[1], acc[2], acc[3]);
    o4[1] = make_float4(acc[4], acc[5], acc[6], acc[7]);
  }
  if (tid == 0) partial[2 * blockIdx.x]     = (sred[0] + sred[1]) + (sred[2] + sred[3]);
  if (tid == 1) partial[2 * blockIdx.x + 1] = (sred[4] + sred[5]) + (sred[6] + sred[7]);
}

// ---------------------------------------------------------------------------
// K2: each of 256 blocks redundantly reduces partial[2048] (L2-hot),
// recomputes the f32 W' fold for per-class sums, then scales 4 float4/thread:
// out = alpha*dot + (beta*wsum[c] + fcb[c]).
__global__ __launch_bounds__(256) void k_scale(float* __restrict__ out,
                                               const float* __restrict__ partial,
                                               const float* __restrict__ fcw,
                                               const float* __restrict__ xs,
                                               const float* __restrict__ ys,
                                               const float* __restrict__ fcb,
                                               const float* __restrict__ bnw,
                                               const float* __restrict__ bnb) {
  __shared__ float sred[8];
  __shared__ float wred[4][8];
  __shared__ float fin[2];
  const int tid = threadIdx.x;
  const int w = tid >> 6, l = tid & 63;

  // batch stats: 1024 block-pairs / 256 threads = 4 each
  float s = 0.0f, q = 0.0f;
  #pragma unroll
  for (int k = 0; k < 4; ++k) {
    const int idx = tid + 256 * k;
    s += partial[2 * idx];
    q += partial[2 * idx + 1];
  }
  #pragma unroll
  for (int off = 32; off; off >>= 1) {
    s += __shfl_xor(s, off, 64);
    q += __shfl_xor(q, off, 64);
  }

  // redundant W' fold for per-class sums (threads 0..127 contribute)
  float v[8];
  if (tid < 128) {
    fold_weights(tid, fcw, xs[0] + 0.5f, ys[0] + 0.5f, v);
  } else {
    #pragma unroll
    for (int c = 0; c < 8; ++c) v[c] = 0.0f;
  }
  #pragma unroll
  for (int c = 0; c < 8; ++c) {
    #pragma unroll
    for (int off = 32; off; off >>= 1) v[c] += __shfl_xor(v[c], off, 64);
  }

  if (l == 0) {
    sred[w] = s; sred[4 + w] = q;
    #pragma unroll
    for (int c = 0; c < 8; ++c) wred[w][c] = v[c];
  }
  __syncthreads();
  if (tid == 0) {
    const float S = (sred[0] + sred[1]) + (sred[2] + sred[3]);
    const float Q = (sred[4] + sred[5]) + (sred[6] + sred[7]);
    const float N = 16777216.0f;  // 131072*128
    const float mm = S / N;
    const float vv = Q / N - mm * mm;
    const float a = bnw[0] / sqrtf(vv + 1e-5f);
    fin[0] = a;
    fin[1] = bnb[0] - mm * a;
  }
  __syncthreads();
  const float alpha = fin[0], beta = fin[1];

  float cv[8];
  #pragma unroll
  for (int c = 0; c < 8; ++c) {
    const float wsum = (wred[0][c] + wred[1][c]) + (wred[2][c] + wred[3][c]);
    cv[c] = fmaf(beta, wsum, fcb[c]);
  }
  const float4 cv0 = make_float4(cv[0], cv[1], cv[2], cv[3]);
  const float4 cv1 = make_float4(cv[4], cv[5], cv[6], cv[7]);

  float4* o4 = (float4*)out;
  const int base = (blockIdx.x * 256 + tid) * 4;  // 4 float4 per thread
  #pragma unroll
  for (int k = 0; k < 4; ++k) {
    const int i = base + k;
    const float4 c = (i & 1) ? cv1 : cv0;
    float4 ov = o4[i];
    ov.x = fmaf(alpha, ov.x, c.x);
    ov.y = fmaf(alpha, ov.y, c.y);
    ov.z = fmaf(alpha, ov.z, c.z);
    ov.w = fmaf(alpha, ov.w, c.w);
    o4[i] = ov;
  }
}

// ---------------------------------------------------------------------------
extern "C" void kernel_launch(void* const* d_in, const int* in_sizes, int n_in,
                              void* d_out, int out_size, void* d_ws, size_t ws_size,
                              hipStream_t stream) {
  const float* x   = (const float*)d_in[0];
  const float* bnw = (const float*)d_in[1];
  const float* bnb = (const float*)d_in[2];
  const float* xs  = (const float*)d_in[3];
  const float* ys  = (const float*)d_in[4];
  const float* fcw = (const float*)d_in[5];
  const float* fcb = (const float*)d_in[6];
  float* out = (float*)d_out;
  float* ws  = (float*)d_ws;

  float* partial = ws;  // 2048 floats

  hipLaunchKernelGGL(k_main,  dim3(NBLK), dim3(256), 0, stream, x, fcw, xs, ys, out, partial);
  hipLaunchKernelGGL(k_scale, dim3(256),  dim3(256), 0, stream, out, partial, fcw, xs, ys, fcb, bnw, bnb);
}

// Round 9
// 42.038 us; speedup vs baseline: 4.5654x; 2.2193x over previous
//
#include <hip/hip_runtime.h>
#include <math.h>

#define NBLK 4096  // k_main: 4096 blocks x 256 thr; 8 threads per image (1 per row)

// ws layout (floats): [0..8191] partial[4096 blocks][2] (sum, sumsq)

__device__ __forceinline__ float med3f(float a, float b, float c) {
  return __builtin_amdgcn_fmed3f(a, b, c);
}
__device__ __forceinline__ float min3f(float a, float b, float c) { return fminf(fminf(a, b), c); }
__device__ __forceinline__ float max3f(float a, float b, float c) { return fmaxf(fmaxf(a, b), c); }

// ---------------------------------------------------------------------------
// Fold shift + FC into W'[c] for pixel p (math validated on HW R1..R8).
__device__ __forceinline__ void fold_weights(int p, const float* __restrict__ fc_w,
                                             float sx, float sy, float* __restrict__ w8) {
  const int y = p >> 4, x = p & 15;
  const int dY = (sy > 1.0f) ? 2 : 1;
  const int dX = (sx > 1.0f) ? 2 : 1;
  const float wy1 = (float)dY - sy, wy0 = 1.0f - wy1;
  const float wx1 = (float)dX - sx, wx0 = 1.0f - wx1;
  const int   iys[2] = { y + dY - 1, y + dY };
  const float wys[2] = { wy1, wy0 };
  const int   jxs[2] = { x + dX - 1, x + dX };
  const float wxs[2] = { wx1, wx0 };
  #pragma unroll
  for (int c = 0; c < 8; ++c) {
    float acc = 0.0f;
    #pragma unroll
    for (int a = 0; a < 2; ++a) {
      if (iys[a] < 0 || iys[a] >= 8) continue;
      #pragma unroll
      for (int b = 0; b < 2; ++b) {
        if (jxs[b] < 0 || jxs[b] >= 16) continue;
        acc += wys[a] * wxs[b] * fc_w[c * 128 + iys[a] * 16 + jxs[b]];
      }
    }
    w8[c] = acc;
  }
}

// ---------------------------------------------------------------------------
// K1: 8 threads per image, one per row. Lane l: image-local g=l>>3, row=l&7.
// Loads rows row-1,row,row+1 (L1 serves the overlap), vertical sort3 in place,
// horizontal median + dot over 16 pixels. Weights f32 in LDS [row][j^row][c]
// (XOR swizzle -> per-wave row addresses land on distinct bank sets). Dot
// partials combined across the 8 row-lanes by a 3-round value-splitting
// butterfly (7 shuffles); lane r ends holding class r -> coalesced 256B/wave
// store. Per-thread ~90-100 VGPR: fits (256,2) cap 128 with NO spill (the
// one-thread-per-image shape needed >128 and spilled in R6/R7/R8).
__global__ __launch_bounds__(256, 2) void k_main(const float* __restrict__ x,
                                                 const float* __restrict__ fcw,
                                                 const float* __restrict__ xs,
                                                 const float* __restrict__ ys,
                                                 float* __restrict__ out,
                                                 float* __restrict__ partial) {
  __shared__ float wlds[8][16][8];  // [row][j^row][c] f32 weights, 4KB
  __shared__ float sred[8];
  const int tid = threadIdx.x;
  const int w = tid >> 6, l = tid & 63;
  const int row = l & 7;
  const int img = blockIdx.x * 32 + w * 8 + (l >> 3);
  const float* __restrict__ xi = x + (size_t)img * 128;

  // 3-row load (clamped rows; zeroed after) — issued first, fold covers latency
  const int rup = (row == 0) ? 0 : row - 1;
  const int rdn = (row == 7) ? 7 : row + 1;
  float up[16], mid[16], dn[16];
  #pragma unroll
  for (int q = 0; q < 4; ++q) {
    *(float4*)&mid[q * 4] = *(const float4*)&xi[row * 16 + q * 4];
    *(float4*)&up[q * 4]  = *(const float4*)&xi[rup * 16 + q * 4];
    *(float4*)&dn[q * 4]  = *(const float4*)&xi[rdn * 16 + q * 4];
  }

  // per-block W' fold into swizzled LDS (threads 0..127, pixel p = tid)
  const float sx = xs[0] + 0.5f, sy = ys[0] + 0.5f;
  if (tid < 128) {
    float w8[8];
    fold_weights(tid, fcw, sx, sy, w8);
    const int r = tid >> 4, j = tid & 15;
    #pragma unroll
    for (int c = 0; c < 8; ++c) wlds[r][j ^ r][c] = w8[c];
  }
  __syncthreads();

  // zero out-of-range rows, then vertical sort3 IN PLACE (keeps live set ~64)
  #pragma unroll
  for (int k = 0; k < 16; ++k) {
    const float a = (row == 0) ? 0.0f : up[k];
    const float b = mid[k];
    const float d = (row == 7) ? 0.0f : dn[k];
    up[k]  = min3f(a, b, d);   // lo
    mid[k] = med3f(a, b, d);   // mi
    dn[k]  = max3f(a, b, d);   // hi
  }

  float acc[8];
  #pragma unroll
  for (int c = 0; c < 8; ++c) acc[c] = 0.0f;
  float ssum = 0.0f, ssq = 0.0f;

  #pragma unroll
  for (int j = 0; j < 16; ++j) {
    const float mx  = max3f((j == 0)  ? 0.0f : up[j - 1],  up[j],
                            (j == 15) ? 0.0f : up[j + 1]);
    const float md  = med3f((j == 0)  ? 0.0f : mid[j - 1], mid[j],
                            (j == 15) ? 0.0f : mid[j + 1]);
    const float mn  = min3f((j == 0)  ? 0.0f : dn[j - 1],  dn[j],
                            (j == 15) ? 0.0f : dn[j + 1]);
    const float med = med3f(mx, md, mn);  // exact lower-median of 9
    ssum += med;
    ssq = fmaf(med, med, ssq);
    const float* wp = &wlds[row][j ^ row][0];
    const float4 w0 = *(const float4*)&wp[0];  // ds_read_b128, bank-spread rows
    const float4 w1 = *(const float4*)&wp[4];
    acc[0] = fmaf(med, w0.x, acc[0]);
    acc[1] = fmaf(med, w0.y, acc[1]);
    acc[2] = fmaf(med, w0.z, acc[2]);
    acc[3] = fmaf(med, w0.w, acc[3]);
    acc[4] = fmaf(med, w1.x, acc[4]);
    acc[5] = fmaf(med, w1.y, acc[5]);
    acc[6] = fmaf(med, w1.z, acc[6]);
    acc[7] = fmaf(med, w1.w, acc[7]);
  }

  // 3-round value-splitting butterfly over the 8 row-lanes (xor 4,2,1):
  // bit set keeps the upper half -> lane ends holding class (l&7).
  const bool b4 = (l & 4) != 0;
  float r4[4];
  #pragma unroll
  for (int j = 0; j < 4; ++j) {
    const float send = b4 ? acc[j] : acc[4 + j];
    const float keep = b4 ? acc[4 + j] : acc[j];
    r4[j] = keep + __shfl_xor(send, 4, 64);
  }
  const bool b2 = (l & 2) != 0;
  float r2[2];
  #pragma unroll
  for (int j = 0; j < 2; ++j) {
    const float send = b2 ? r4[j] : r4[2 + j];
    const float keep = b2 ? r4[2 + j] : r4[j];
    r2[j] = keep + __shfl_xor(send, 2, 64);
  }
  const bool b1 = (l & 1) != 0;
  {
    const float send = b1 ? r2[0] : r2[1];
    const float keep = b1 ? r2[1] : r2[0];
    const float r = keep + __shfl_xor(send, 1, 64);
    out[(size_t)img * 8 + (l & 7)] = r;  // lane-consecutive -> 256B/wave
  }

  // stats: wave reduce then block reduce
  #pragma unroll
  for (int off = 32; off; off >>= 1) {
    ssum += __shfl_xor(ssum, off, 64);
    ssq  += __shfl_xor(ssq,  off, 64);
  }
  if (l == 0) { sred[w] = ssum; sred[4 + w] = ssq; }
  __syncthreads();
  if (tid == 0) partial[2 * blockIdx.x]     = (sred[0] + sred[1]) + (sred[2] + sred[3]);
  if (tid == 1) partial[2 * blockIdx.x + 1] = (sred[4] + sred[5]) + (sred[6] + sred[7]);
}

// ---------------------------------------------------------------------------
// K2: each of 256 blocks redundantly reduces partial[8192] (L2-hot),
// recomputes the f32 W' fold for per-class sums, then scales 4 float4/thread:
// out = alpha*dot + (beta*wsum[c] + fcb[c]).
__global__ __launch_bounds__(256) void k_scale(float* __restrict__ out,
                                               const float* __restrict__ partial,
                                               const float* __restrict__ fcw,
                                               const float* __restrict__ xs,
                                               const float* __restrict__ ys,
                                               const float* __restrict__ fcb,
                                               const float* __restrict__ bnw,
                                               const float* __restrict__ bnb) {
  __shared__ float sred[8];
  __shared__ float wred[4][8];
  __shared__ float fin[2];
  const int tid = threadIdx.x;
  const int w = tid >> 6, l = tid & 63;

  // batch stats: 4096 block-pairs / 256 threads = 16 each
  float s = 0.0f, q = 0.0f;
  #pragma unroll
  for (int k = 0; k < 16; ++k) {
    const int idx = tid + 256 * k;
    s += partial[2 * idx];
    q += partial[2 * idx + 1];
  }
  #pragma unroll
  for (int off = 32; off; off >>= 1) {
    s += __shfl_xor(s, off, 64);
    q += __shfl_xor(q, off, 64);
  }

  // redundant W' fold for per-class sums (threads 0..127 contribute)
  float v[8];
  if (tid < 128) {
    fold_weights(tid, fcw, xs[0] + 0.5f, ys[0] + 0.5f, v);
  } else {
    #pragma unroll
    for (int c = 0; c < 8; ++c) v[c] = 0.0f;
  }
  #pragma unroll
  for (int c = 0; c < 8; ++c) {
    #pragma unroll
    for (int off = 32; off; off >>= 1) v[c] += __shfl_xor(v[c], off, 64);
  }

  if (l == 0) {
    sred[w] = s; sred[4 + w] = q;
    #pragma unroll
    for (int c = 0; c < 8; ++c) wred[w][c] = v[c];
  }
  __syncthreads();
  if (tid == 0) {
    const float S = (sred[0] + sred[1]) + (sred[2] + sred[3]);
    const float Q = (sred[4] + sred[5]) + (sred[6] + sred[7]);
    const float N = 16777216.0f;  // 131072*128
    const float mm = S / N;
    const float vv = Q / N - mm * mm;
    const float a = bnw[0] / sqrtf(vv + 1e-5f);
    fin[0] = a;
    fin[1] = bnb[0] - mm * a;
  }
  __syncthreads();
  const float alpha = fin[0], beta = fin[1];

  float cv[8];
  #pragma unroll
  for (int c = 0; c < 8; ++c) {
    const float wsum = (wred[0][c] + wred[1][c]) + (wred[2][c] + wred[3][c]);
    cv[c] = fmaf(beta, wsum, fcb[c]);
  }
  const float4 cv0 = make_float4(cv[0], cv[1], cv[2], cv[3]);
  const float4 cv1 = make_float4(cv[4], cv[5], cv[6], cv[7]);

  float4* o4 = (float4*)out;
  const int base = (blockIdx.x * 256 + tid) * 4;  // 4 float4 per thread
  #pragma unroll
  for (int k = 0; k < 4; ++k) {
    const int i = base + k;
    const float4 c = (i & 1) ? cv1 : cv0;
    float4 ov = o4[i];
    ov.x = fmaf(alpha, ov.x, c.x);
    ov.y = fmaf(alpha, ov.y, c.y);
    ov.z = fmaf(alpha, ov.z, c.z);
    ov.w = fmaf(alpha, ov.w, c.w);
    o4[i] = ov;
  }
}

// ---------------------------------------------------------------------------
extern "C" void kernel_launch(void* const* d_in, const int* in_sizes, int n_in,
                              void* d_out, int out_size, void* d_ws, size_t ws_size,
                              hipStream_t stream) {
  const float* x   = (const float*)d_in[0];
  const float* bnw = (const float*)d_in[1];
  const float* bnb = (const float*)d_in[2];
  const float* xs  = (const float*)d_in[3];
  const float* ys  = (const float*)d_in[4];
  const float* fcw = (const float*)d_in[5];
  const float* fcb = (const float*)d_in[6];
  float* out = (float*)d_out;
  float* ws  = (float*)d_ws;

  float* partial = ws;  // 8192 floats

  hipLaunchKernelGGL(k_main,  dim3(NBLK), dim3(256), 0, stream, x, fcw, xs, ys, out, partial);
  hipLaunchKernelGGL(k_scale, dim3(256),  dim3(256), 0, stream, out, partial, fcw, xs, ys, fcb, bnw, bnb);
}